// Round 30
// baseline (113.231 us; speedup 1.0000x reference)
//
#include <hip/hip_runtime.h>
#include <hip/hip_bf16.h>
#include <stdint.h>

#define B_ 2
#define S_ 2048
#define H_ 32
#define D_ 128
#define R_ (B_*H_*S_)           // 131072 (b,h,s) rows
#define PG 2048                 // prep grid size
#define CPB 132                 // uniform 8-subtile chunks per bh (q64 units)

typedef __bf16 bf16x8 __attribute__((ext_vector_type(8)));
typedef float  f32x16 __attribute__((ext_vector_type(16)));

#if __has_builtin(__builtin_amdgcn_exp2f)
#define EXP2F(x) __builtin_amdgcn_exp2f(x)
#else
#define EXP2F(x) exp2f(x)
#endif

#define AS1 __attribute__((address_space(1)))
#define AS3 __attribute__((address_space(3)))

__device__ __forceinline__ unsigned short f2bf(float f) {
  unsigned u = __float_as_uint(f);
  u += 0x7FFFu + ((u >> 16) & 1u);
  return (unsigned short)(u >> 16);
}

__device__ __forceinline__ unsigned int cvtpk(float a, float b) {
  unsigned int r;
  asm("v_cvt_pk_bf16_f32 %0, %1, %2" : "=v"(r) : "v"(a), "v"(b));
  return r;
}

// Prep (R26-exact): K convert only (+vsum+zeroing). Footprint:
// q+k+v+kc = 224MB < 256MB L3 -> replay traffic L3-served.
__global__ __launch_bounds__(256) void prep(
    const float* __restrict__ kf, const float* __restrict__ v,
    unsigned short* __restrict__ kc,
    float* __restrict__ vsum, float* __restrict__ nd, float* __restrict__ out0) {
  const int bid = blockIdx.x;
  const int t = threadIdx.x;
  if (bid == 0 && t == 0) out0[0] = 0.f;

  #pragma unroll
  for (int g = 0; g < 4; ++g) {                 // k: 4 ushort8-units/thread
    const size_t i = (size_t)g * (PG * 256) + (size_t)bid * 256 + t;
    const float4 a = *reinterpret_cast<const float4*>(kf + i * 8);
    const float4 b = *reinterpret_cast<const float4*>(kf + i * 8 + 4);
    union { unsigned short u[8]; uint4 v4; } o;
    o.u[0] = f2bf(a.x); o.u[1] = f2bf(a.y);
    o.u[2] = f2bf(a.z); o.u[3] = f2bf(a.w);
    o.u[4] = f2bf(b.x); o.u[5] = f2bf(b.y);
    o.u[6] = f2bf(b.z); o.u[7] = f2bf(b.w);
    *reinterpret_cast<uint4*>(kc + i * 8) = o.v4;
  }

  #pragma unroll
  for (int g = 0; g < (B_ * S_) / PG; ++g) {    // vsum: 2 panels/block
    const int u = bid + g * PG;
    const int b = u / S_, s = u % S_;
    const float4* panel =
        reinterpret_cast<const float4*>(v + (((size_t)b * S_ + s) * H_) * D_);
    #pragma unroll
    for (int j = 0; j < 4; ++j) {
      const float4 a = panel[j * 256 + t];
      float sum = a.x + a.y + a.z + a.w;
      sum += __shfl_xor(sum, 1);
      sum += __shfl_xor(sum, 2);
      sum += __shfl_xor(sum, 4);
      sum += __shfl_xor(sum, 8);
      sum += __shfl_xor(sum, 16);
      const int h = j * 8 + (t >> 5);           // 32-lane group owns one h-row
      if ((t & 31) == 0) vsum[((size_t)b * H_ + h) * S_ + s] = sum;
    }
  }

  if (bid < 256) {
    float4* p = reinterpret_cast<float4*>(nd);
    p[(size_t)bid * 256 + t] = float4{0.f, 0.f, 0.f, 0.f};
  }
}

// Main: FULLY WAVE-INDEPENDENT (64-thread blocks, ZERO barriers -- 7 stall
// theories inside the 4-wave lockstep skeleton were falsified; this removes
// the lockstep itself while KEEPING the proven DMA prefetch pipeline that
// R5/R28's barrier-free attempts lacked). Each wave: uniform 8-subtile chunk
// of flattened (q-tile64 j, k-subtile st) units; wave-private ring-2 LDS
// (16.5KB/block -> 9 blocks/CU, fine-grain backfill); counted vmcnt(9) keeps
// one 9-op batch in flight; lgkmcnt(0) before overwriting the consumed slot.
// Q = 2 sides x 32 cols from fp32 (reloaded on j-change, scale folded);
// swapped mfma(K,Q); XOR-involution staging from bf16 kc.
__global__ __launch_bounds__(64, 4) void attn_sum(
    const float* __restrict__ qf, const unsigned short* __restrict__ kc,
    const float* __restrict__ vsum, float* __restrict__ numb,
    float* __restrict__ denb) {
  __shared__ uint4 kbuf[2][512];       // 2 x 8KB (wave-private)
  __shared__ float vsbuf[2][64];       // 2 x 256B

  const int id = blockIdx.x;           // 8448 blocks = 64 bh x 132 chunks
  const int y  = id >> 3;              // 0..1055
  const int bh = (id & 7) + 8 * (y / CPB);
  const int c  = y % CPB;

  const int l  = threadIdx.x;          // 0..63
  const int ln = l & 31, l5 = l >> 5;

  const int b0 = bh >> 5, h0 = bh & 31;
  const unsigned short* kc0 = kc + ((size_t)b0 * S_ * H_ + h0) * D_;
  const float* vsrc0 = vsum + (size_t)bh * S_;
  float* nrow = numb + (size_t)bh * S_;
  float* drow = denb + (size_t)bh * S_;

  // Flattened units: q-tile64 j contributes 2j+2 k-subtiles; prefix j(j+1).
  const int f0 = c * 8, fend = f0 + 8;
  int j = 0;
  while ((j + 1) * (j + 2) <= f0) ++j;
  int st = f0 - j * (j + 1);

  // Stage one 32-row K-subtile (8 K-DMAs of 1KB) + vsum strip = 9 vmcnt ops.
  auto stage = [&](int stk, int slot) {
    #pragma unroll
    for (int i = 0; i < 8; ++i) {
      const int idx = i * 64 + l;
      const int r   = idx >> 4;
      const int p   = idx & 15;
      const int cc  = p ^ (r & 15);
      const unsigned short* src = kc0 + (size_t)(stk * 32 + r) * (H_ * D_) + cc * 8;
      __builtin_amdgcn_global_load_lds(
          (const AS1 void*)src, (AS3 void*)(&kbuf[slot][idx & ~63]), 16, 0, 0);
    }
    __builtin_amdgcn_global_load_lds(
        (const AS1 void*)(vsrc0 + stk * 32 + l), (AS3 void*)(&vsbuf[slot][0]), 4, 0, 0);
  };

  const float sc = 0.0883883476483184f * 1.4426950408889634f;
  bf16x8 qfA[8], qfB[8];
  auto loadQ = [&](int jq) {
    const float* qpA = qf + (((size_t)b0 * S_ + jq * 64 + ln) * H_ + h0) * D_ + l5 * 8;
    const float* qpB = qpA + (size_t)32 * (H_ * D_);
    #pragma unroll
    for (int kb8 = 0; kb8 < 8; ++kb8) {
      float4 a = *reinterpret_cast<const float4*>(qpA + kb8 * 16);
      float4 b = *reinterpret_cast<const float4*>(qpA + kb8 * 16 + 4);
      union { unsigned int u[4]; bf16x8 v; } oA;
      oA.u[0] = cvtpk(a.x * sc, a.y * sc); oA.u[1] = cvtpk(a.z * sc, a.w * sc);
      oA.u[2] = cvtpk(b.x * sc, b.y * sc); oA.u[3] = cvtpk(b.z * sc, b.w * sc);
      qfA[kb8] = oA.v;
      a = *reinterpret_cast<const float4*>(qpB + kb8 * 16);
      b = *reinterpret_cast<const float4*>(qpB + kb8 * 16 + 4);
      union { unsigned int u[4]; bf16x8 v; } oB;
      oB.u[0] = cvtpk(a.x * sc, a.y * sc); oB.u[1] = cvtpk(a.z * sc, a.w * sc);
      oB.u[2] = cvtpk(b.x * sc, b.y * sc); oB.u[3] = cvtpk(b.z * sc, b.w * sc);
      qfB[kb8] = oB.v;
    }
  };

  float npA = 0.f, dpA = 0.f, npB = 0.f, dpB = 0.f;
  auto flush = [&](int jq) {
    npA += __shfl_xor(npA, 32); dpA += __shfl_xor(dpA, 32);
    npB += __shfl_xor(npB, 32); dpB += __shfl_xor(dpB, 32);
    if (l5 == 0) {
      atomicAdd(&nrow[jq * 64 + ln], npA);
      atomicAdd(&drow[jq * 64 + ln], dpA);
      atomicAdd(&nrow[jq * 64 + 32 + ln], npB);
      atomicAdd(&drow[jq * 64 + 32 + ln], dpB);
    }
    npA = dpA = npB = dpB = 0.f;
  };

  // Staging tracker (unit fs with coords js, sts).
  int fs = f0, js = j, sts = st;
  auto advS = [&]() { ++fs; ++sts; if (sts == 2 * js + 2) { sts = 0; ++js; } };

  stage(sts, fs & 1); advS();
  if (fs < fend) { stage(sts, fs & 1); advS(); }

  int jq = j;
  loadQ(jq);

  const int xr = ln & 15;
  for (int f = f0; f < fend; ++f) {
    if (j != jq) { flush(jq); jq = j; loadQ(jq); }

    if (f + 1 < fend) asm volatile("s_waitcnt vmcnt(9)" ::: "memory");
    else              asm volatile("s_waitcnt vmcnt(0)" ::: "memory");

    const int slot = f & 1;
    const uint4* rowb = &kbuf[slot][ln * 16];
    bf16x8 kfr[8];
    #pragma unroll
    for (int kb8 = 0; kb8 < 8; ++kb8)
      kfr[kb8] = *reinterpret_cast<const bf16x8*>(&rowb[(kb8 * 2 + l5) ^ xr]);
    const float4 vs0 = *reinterpret_cast<const float4*>(&vsbuf[slot][ 0 + 4 * l5]);
    const float4 vs1 = *reinterpret_cast<const float4*>(&vsbuf[slot][ 8 + 4 * l5]);
    const float4 vs2 = *reinterpret_cast<const float4*>(&vsbuf[slot][16 + 4 * l5]);
    const float4 vs3 = *reinterpret_cast<const float4*>(&vsbuf[slot][24 + 4 * l5]);
    const float vsa[16] = {vs0.x,vs0.y,vs0.z,vs0.w, vs1.x,vs1.y,vs1.z,vs1.w,
                           vs2.x,vs2.y,vs2.z,vs2.w, vs3.x,vs3.y,vs3.z,vs3.w};
    // Frags + vs are in registers; safe to overwrite this slot now.
    asm volatile("s_waitcnt lgkmcnt(0)" ::: "memory");
    __builtin_amdgcn_sched_barrier(0);
    if (fs < fend) { stage(sts, fs & 1); advS(); }

    const int kbase = st * 32;
    // ---- side A: full when st < 2j, diag when st == 2j, skip st == 2j+1 ----
    if (st <= 2 * j) {
      f32x16 sacc = {0.f,0.f,0.f,0.f,0.f,0.f,0.f,0.f,
                     0.f,0.f,0.f,0.f,0.f,0.f,0.f,0.f};
      __builtin_amdgcn_s_setprio(1);
      #pragma unroll
      for (int kb8 = 0; kb8 < 8; ++kb8)
        sacc = __builtin_amdgcn_mfma_f32_32x32x16_bf16(kfr[kb8], qfA[kb8], sacc, 0, 0, 0);
      __builtin_amdgcn_s_setprio(0);
      if (st < 2 * j) {
        #pragma unroll
        for (int r = 0; r < 16; ++r) {
          const float e = EXP2F(sacc[r]);
          dpA += e; npA = fmaf(e, vsa[r], npA);
        }
      } else {
        const int qg = j * 64 + ln;
        #pragma unroll
        for (int r = 0; r < 16; ++r) {
          const int kr = kbase + (r & 3) + 8 * (r >> 2) + 4 * l5;
          const float e = (kr <= qg) ? EXP2F(sacc[r]) : 0.f;
          dpA += e; npA = fmaf(e, vsa[r], npA);
        }
      }
    }
    // ---- side B: full when st < 2j+1, diag when st == 2j+1 ----
    {
      f32x16 sacc = {0.f,0.f,0.f,0.f,0.f,0.f,0.f,0.f,
                     0.f,0.f,0.f,0.f,0.f,0.f,0.f,0.f};
      __builtin_amdgcn_s_setprio(1);
      #pragma unroll
      for (int kb8 = 0; kb8 < 8; ++kb8)
        sacc = __builtin_amdgcn_mfma_f32_32x32x16_bf16(kfr[kb8], qfB[kb8], sacc, 0, 0, 0);
      __builtin_amdgcn_s_setprio(0);
      if (st < 2 * j + 1) {
        #pragma unroll
        for (int r = 0; r < 16; ++r) {
          const float e = EXP2F(sacc[r]);
          dpB += e; npB = fmaf(e, vsa[r], npB);
        }
      } else {
        const int qg = j * 64 + 32 + ln;
        #pragma unroll
        for (int r = 0; r < 16; ++r) {
          const int kr = kbase + (r & 3) + 8 * (r >> 2) + 4 * l5;
          const float e = (kr <= qg) ? EXP2F(sacc[r]) : 0.f;
          dpB += e; npB = fmaf(e, vsa[r], npB);
        }
      }
    }

    // advance main coords
    ++st;
    if (st == 2 * j + 2) { st = 0; ++j; }
  }
  flush(jq);
}

// Finalize: sum(num/den) over all q-rows.
__global__ __launch_bounds__(256) void finalize(
    const float* __restrict__ numb, const float* __restrict__ denb,
    float* __restrict__ out) {
  const int i = blockIdx.x * 256 + threadIdx.x;
  float c = numb[i] / denb[i];
  #pragma unroll
  for (int m = 1; m < 64; m <<= 1) c += __shfl_xor(c, m);
  __shared__ float ps[4];
  if ((threadIdx.x & 63) == 0) ps[threadIdx.x >> 6] = c;
  __syncthreads();
  if (threadIdx.x == 0) atomicAdd(out, ps[0] + ps[1] + ps[2] + ps[3]);
}

extern "C" void kernel_launch(void* const* d_in, const int* in_sizes, int n_in,
                              void* d_out, int out_size, void* d_ws, size_t ws_size,
                              hipStream_t stream) {
  const float* q = (const float*)d_in[0];
  const float* k = (const float*)d_in[1];
  const float* v = (const float*)d_in[2];
  float* out = (float*)d_out;

  unsigned short* kc = (unsigned short*)d_ws;                 // 32 MiB
  float* vsum = (float*)(kc + (size_t)R_ * D_);               // 512 KiB
  float* numb = vsum + R_;                                    // 512 KiB
  float* denb = numb + R_;                                    // 512 KiB

  hipLaunchKernelGGL(prep, dim3(PG), dim3(256), 0, stream,
                     k, v, kc, vsum, numb, out);
  hipLaunchKernelGGL(attn_sum, dim3(64 * CPB * 8 / 8), dim3(64), 0, stream,
                     q, kc, vsum, numb, denb);
  hipLaunchKernelGGL(finalize, dim3(R_ / 256), dim3(256), 0, stream,
                     numb, denb, out);
}

// Round 31
// 98.839 us; speedup vs baseline: 1.1456x; 1.1456x over previous
//
#include <hip/hip_runtime.h>
#include <hip/hip_bf16.h>
#include <stdint.h>

#define B_ 2
#define S_ 2048
#define H_ 32
#define D_ 128
#define R_ (B_*H_*S_)           // 131072 (b,h,s) rows
#define PG 2048                 // prep grid size
#define CPB 27                  // k-chunks per bh (pair structure, <=6 tiles)

typedef __bf16 bf16x8 __attribute__((ext_vector_type(8)));
typedef float  f32x16 __attribute__((ext_vector_type(16)));

#if __has_builtin(__builtin_amdgcn_exp2f)
#define EXP2F(x) __builtin_amdgcn_exp2f(x)
#else
#define EXP2F(x) exp2f(x)
#endif

#define AS1 __attribute__((address_space(1)))
#define AS3 __attribute__((address_space(3)))

__device__ __forceinline__ unsigned short f2bf(float f) {
  unsigned u = __float_as_uint(f);
  u += 0x7FFFu + ((u >> 16) & 1u);
  return (unsigned short)(u >> 16);
}

__device__ __forceinline__ unsigned int cvtpk(float a, float b) {
  unsigned int r;
  asm("v_cvt_pk_bf16_f32 %0, %1, %2" : "=v"(r) : "v"(a), "v"(b));
  return r;
}

// Prep (R21-identical): K convert only (+vsum+zeroing). Footprint:
// q+k+v+kc = 224MB < 256MB L3 -> replay traffic L3-served.
__global__ __launch_bounds__(256) void prep(
    const float* __restrict__ kf, const float* __restrict__ v,
    unsigned short* __restrict__ kc,
    float* __restrict__ vsum, float* __restrict__ nd, float* __restrict__ out0) {
  const int bid = blockIdx.x;
  const int t = threadIdx.x;
  if (bid == 0 && t == 0) out0[0] = 0.f;

  #pragma unroll
  for (int g = 0; g < 4; ++g) {                 // k: 4 ushort8-units/thread
    const size_t i = (size_t)g * (PG * 256) + (size_t)bid * 256 + t;
    const float4 a = *reinterpret_cast<const float4*>(kf + i * 8);
    const float4 b = *reinterpret_cast<const float4*>(kf + i * 8 + 4);
    union { unsigned short u[8]; uint4 v4; } o;
    o.u[0] = f2bf(a.x); o.u[1] = f2bf(a.y);
    o.u[2] = f2bf(a.z); o.u[3] = f2bf(a.w);
    o.u[4] = f2bf(b.x); o.u[5] = f2bf(b.y);
    o.u[6] = f2bf(b.z); o.u[7] = f2bf(b.w);
    *reinterpret_cast<uint4*>(kc + i * 8) = o.v4;
  }

  #pragma unroll
  for (int g = 0; g < (B_ * S_) / PG; ++g) {    // vsum: 2 panels/block
    const int u = bid + g * PG;
    const int b = u / S_, s = u % S_;
    const float4* panel =
        reinterpret_cast<const float4*>(v + (((size_t)b * S_ + s) * H_) * D_);
    #pragma unroll
    for (int j = 0; j < 4; ++j) {
      const float4 a = panel[j * 256 + t];
      float sum = a.x + a.y + a.z + a.w;
      sum += __shfl_xor(sum, 1);
      sum += __shfl_xor(sum, 2);
      sum += __shfl_xor(sum, 4);
      sum += __shfl_xor(sum, 8);
      sum += __shfl_xor(sum, 16);
      const int h = j * 8 + (t >> 5);           // 32-lane group owns one h-row
      if ((t & 31) == 0) vsum[((size_t)b * H_ + h) * S_ + s] = sum;
    }
  }

  if (bid < 256) {
    float4* p = reinterpret_cast<float4*>(nd);
    p[(size_t)bid * 256 + t] = float4{0.f, 0.f, 0.f, 0.f};
  }
}

// Main: R24-EXACT (best measured: bench 99.27us) with ONE isolated change:
// s_setprio REMOVED. m190 evidence: setprio is net-negative in lockstep
// barrier structures (it starves co-resident blocks' staging waves on the
// same CU). Zero register/LDS impact -> clean A/B vs R24. Everything else
// unchanged: q-pair sharing, swapped mfma(K,Q), ring-4 LDS, depth-2
// early-issue prefetch, counted vmcnt(6/3/0), raw s_barrier, XOR-involution
// DMA staging from bf16 kc, fp32 Q + cvt_pk.
__global__ __launch_bounds__(256, 3) void attn_sum(
    const float* __restrict__ qf, const unsigned short* __restrict__ kc,
    const float* __restrict__ vsum, float* __restrict__ numb,
    float* __restrict__ denb) {
  __shared__ uint4 kbuf[4][512];       // 4 x 8KB
  __shared__ float vsbuf[4][64];       // 4 x 256B

  const int id = blockIdx.x;
  const int y  = id >> 3;
  const int bh = (id & 7) + 8 * (y / CPB);
  const int c  = y % CPB;

  // pair g has 4g+4 k-tiles -> chunks: 1,2,2,3,4,4,5,6 per g.
  int g, h, nch;
  if (c < 1)       { g = 0; h = c;      nch = 1; }
  else if (c < 3)  { g = 1; h = c - 1;  nch = 2; }
  else if (c < 5)  { g = 2; h = c - 3;  nch = 2; }
  else if (c < 8)  { g = 3; h = c - 5;  nch = 3; }
  else if (c < 12) { g = 4; h = c - 8;  nch = 4; }
  else if (c < 16) { g = 5; h = c - 12; nch = 4; }
  else if (c < 21) { g = 6; h = c - 16; nch = 5; }
  else             { g = 7; h = c - 21; nch = 6; }
  const int nkt  = 4 * g + 4;
  const int bas_ = nkt / nch, rem = nkt % nch;
  const int kt0  = h * bas_ + (h < rem ? h : rem);
  const int kt1  = kt0 + bas_ + (h < rem ? 1 : 0);
  const int st0  = 2 * kt0, st1 = 2 * kt1;   // 32-row subtiles

  const int t  = threadIdx.x;
  const int w  = t >> 6;
  const int l  = t & 63;
  const int ln = l & 31, l5 = l >> 5;

  const int b0 = bh >> 5, h0 = bh & 31;
  const int qminA = (2 * g) * 128 + w * 32;
  const int qminB = (2 * g + 1) * 128 + w * 32;
  const unsigned short* kc0 = kc + ((size_t)b0 * S_ * H_ + h0) * D_;
  const float* vsrc0 = vsum + (size_t)bh * S_;

  // Q B-frags for both tiles from fp32 (scale*log2e folded), once per block.
  const float sc = 0.0883883476483184f * 1.4426950408889634f;
  bf16x8 qfA[8], qfB[8];
  {
    const float* qpA = qf + (((size_t)b0 * S_ + qminA + ln) * H_ + h0) * D_ + l5 * 8;
    const float* qpB = qf + (((size_t)b0 * S_ + qminB + ln) * H_ + h0) * D_ + l5 * 8;
    #pragma unroll
    for (int kb8 = 0; kb8 < 8; ++kb8) {
      float4 a = *reinterpret_cast<const float4*>(qpA + kb8 * 16);
      float4 b = *reinterpret_cast<const float4*>(qpA + kb8 * 16 + 4);
      union { unsigned int u[4]; bf16x8 v; } oA;
      oA.u[0] = cvtpk(a.x * sc, a.y * sc); oA.u[1] = cvtpk(a.z * sc, a.w * sc);
      oA.u[2] = cvtpk(b.x * sc, b.y * sc); oA.u[3] = cvtpk(b.z * sc, b.w * sc);
      qfA[kb8] = oA.v;
      a = *reinterpret_cast<const float4*>(qpB + kb8 * 16);
      b = *reinterpret_cast<const float4*>(qpB + kb8 * 16 + 4);
      union { unsigned int u[4]; bf16x8 v; } oB;
      oB.u[0] = cvtpk(a.x * sc, a.y * sc); oB.u[1] = cvtpk(a.z * sc, a.w * sc);
      oB.u[2] = cvtpk(b.x * sc, b.y * sc); oB.u[3] = cvtpk(b.z * sc, b.w * sc);
      qfB[kb8] = oB.v;
    }
  }

  // Stage one 32-row subtile: 2 K-DMAs + 1 vsum-DMA = 3 vmcnt ops.
  auto stage = [&](int st, int slot) {
    #pragma unroll
    for (int j = 0; j < 2; ++j) {
      const int idx = (w * 2 + j) * 64 + l;   // physical 16B slot in subtile
      const int r   = idx >> 4;
      const int p   = idx & 15;
      const int cc  = p ^ (r & 15);           // logical chunk stored here
      const unsigned short* src = kc0 + (size_t)(st * 32 + r) * (H_ * D_) + cc * 8;
      __builtin_amdgcn_global_load_lds(
          (const AS1 void*)src, (AS3 void*)(&kbuf[slot][idx & ~63]), 16, 0, 0);
    }
    __builtin_amdgcn_global_load_lds(
        (const AS1 void*)(vsrc0 + st * 32 + l), (AS3 void*)(&vsbuf[slot][0]), 4, 0, 0);
  };

  float npA = 0.f, dpA = 0.f, npB = 0.f, dpB = 0.f;

  // Prologue: depth-2.
  stage(st0, st0 & 3);
  stage(st0 + 1, (st0 + 1) & 3);

  const int xr = ln & 15;
  for (int st = st0; st < st1; ++st) {
    // Early issue of st+2, then counted wait for batch st.
    if (st + 2 < st1) {
      stage(st + 2, (st + 2) & 3);
      __builtin_amdgcn_sched_barrier(0);
      asm volatile("s_waitcnt vmcnt(6)" ::: "memory");
    } else if (st + 1 < st1) {
      asm volatile("s_waitcnt vmcnt(3)" ::: "memory");
    } else {
      asm volatile("s_waitcnt vmcnt(0)" ::: "memory");
    }
    __builtin_amdgcn_s_barrier();            // raw: prefetches stay in flight

    const int kbase = st * 32;
    if (kbase <= qminB + 31) {               // B active (A-active implies this)
      const int slot = st & 3;
      const uint4* rowb = &kbuf[slot][ln * 16];
      bf16x8 kfr[8];
      #pragma unroll
      for (int kb8 = 0; kb8 < 8; ++kb8)
        kfr[kb8] = *reinterpret_cast<const bf16x8*>(&rowb[(kb8 * 2 + l5) ^ xr]);
      const float4 vs0 = *reinterpret_cast<const float4*>(&vsbuf[slot][ 0 + 4 * l5]);
      const float4 vs1 = *reinterpret_cast<const float4*>(&vsbuf[slot][ 8 + 4 * l5]);
      const float4 vs2 = *reinterpret_cast<const float4*>(&vsbuf[slot][16 + 4 * l5]);
      const float4 vs3 = *reinterpret_cast<const float4*>(&vsbuf[slot][24 + 4 * l5]);
      const float vsa[16] = {vs0.x,vs0.y,vs0.z,vs0.w, vs1.x,vs1.y,vs1.z,vs1.w,
                             vs2.x,vs2.y,vs2.z,vs2.w, vs3.x,vs3.y,vs3.z,vs3.w};

      // ---- side B ----
      {
        f32x16 sacc = {0.f,0.f,0.f,0.f,0.f,0.f,0.f,0.f,
                       0.f,0.f,0.f,0.f,0.f,0.f,0.f,0.f};
        #pragma unroll
        for (int kb8 = 0; kb8 < 8; ++kb8)
          sacc = __builtin_amdgcn_mfma_f32_32x32x16_bf16(kfr[kb8], qfB[kb8], sacc, 0, 0, 0);
        if (kbase + 31 <= qminB) {
          #pragma unroll
          for (int r = 0; r < 16; ++r) {
            const float e = EXP2F(sacc[r]);
            dpB += e;
            npB = fmaf(e, vsa[r], npB);
          }
        } else {
          const int qg = qminB + ln;
          #pragma unroll
          for (int r = 0; r < 16; ++r) {
            const int kr = kbase + (r & 3) + 8 * (r >> 2) + 4 * l5;
            const float e = (kr <= qg) ? EXP2F(sacc[r]) : 0.f;
            dpB += e;
            npB = fmaf(e, vsa[r], npB);
          }
        }
      }
      // ---- side A ----
      if (kbase <= qminA + 31) {
        f32x16 sacc = {0.f,0.f,0.f,0.f,0.f,0.f,0.f,0.f,
                       0.f,0.f,0.f,0.f,0.f,0.f,0.f,0.f};
        #pragma unroll
        for (int kb8 = 0; kb8 < 8; ++kb8)
          sacc = __builtin_amdgcn_mfma_f32_32x32x16_bf16(kfr[kb8], qfA[kb8], sacc, 0, 0, 0);
        if (kbase + 31 <= qminA) {
          #pragma unroll
          for (int r = 0; r < 16; ++r) {
            const float e = EXP2F(sacc[r]);
            dpA += e;
            npA = fmaf(e, vsa[r], npA);
          }
        } else {
          const int qg = qminA + ln;
          #pragma unroll
          for (int r = 0; r < 16; ++r) {
            const int kr = kbase + (r & 3) + 8 * (r >> 2) + 4 * l5;
            const float e = (kr <= qg) ? EXP2F(sacc[r]) : 0.f;
            dpA += e;
            npA = fmaf(e, vsa[r], npA);
          }
        }
      }
    }
  }

  // Combine l5 halves (same q-col, disjoint k-rows); 2 atomic pairs per col.
  npA += __shfl_xor(npA, 32); dpA += __shfl_xor(dpA, 32);
  npB += __shfl_xor(npB, 32); dpB += __shfl_xor(dpB, 32);
  if (l5 == 0) {
    float* nrow = numb + (size_t)bh * S_;
    float* drow = denb + (size_t)bh * S_;
    atomicAdd(&nrow[qminA + ln], npA);
    atomicAdd(&drow[qminA + ln], dpA);
    atomicAdd(&nrow[qminB + ln], npB);
    atomicAdd(&drow[qminB + ln], dpB);
  }
}

// Finalize: sum(num/den) over all q-rows.
__global__ __launch_bounds__(256) void finalize(
    const float* __restrict__ numb, const float* __restrict__ denb,
    float* __restrict__ out) {
  const int i = blockIdx.x * 256 + threadIdx.x;
  float c = numb[i] / denb[i];
  #pragma unroll
  for (int m = 1; m < 64; m <<= 1) c += __shfl_xor(c, m);
  __shared__ float ps[4];
  if ((threadIdx.x & 63) == 0) ps[threadIdx.x >> 6] = c;
  __syncthreads();
  if (threadIdx.x == 0) atomicAdd(out, ps[0] + ps[1] + ps[2] + ps[3]);
}

extern "C" void kernel_launch(void* const* d_in, const int* in_sizes, int n_in,
                              void* d_out, int out_size, void* d_ws, size_t ws_size,
                              hipStream_t stream) {
  const float* q = (const float*)d_in[0];
  const float* k = (const float*)d_in[1];
  const float* v = (const float*)d_in[2];
  float* out = (float*)d_out;

  unsigned short* kc = (unsigned short*)d_ws;                 // 32 MiB
  float* vsum = (float*)(kc + (size_t)R_ * D_);               // 512 KiB
  float* numb = vsum + R_;                                    // 512 KiB
  float* denb = numb + R_;                                    // 512 KiB

  hipLaunchKernelGGL(prep, dim3(PG), dim3(256), 0, stream,
                     k, v, kc, vsum, numb, out);
  hipLaunchKernelGGL(attn_sum, dim3(64 * CPB), dim3(256), 0, stream,
                     q, kc, vsum, numb, denb);
  hipLaunchKernelGGL(finalize, dim3(R_ / 256), dim3(256), 0, stream,
                     numb, denb, out);
}